// Round 4
// baseline (195.909 us; speedup 1.0000x reference)
//
#include <hip/hip_runtime.h>
#include <hip/hip_bf16.h>

typedef __attribute__((ext_vector_type(8))) short bf16x8;
typedef __attribute__((ext_vector_type(4))) short s16x4;
typedef __attribute__((ext_vector_type(4))) float f32x4;
typedef __attribute__((ext_vector_type(4))) int   i32x4;
typedef unsigned int u32;

__device__ inline short f2bf(float f){
  union { float f; unsigned u; } v; v.f = f;
  unsigned r = v.u + 0x7fffu + ((v.u >> 16) & 1u);   // RNE
  return (short)(r >> 16);
}

__device__ __forceinline__ void gll16(const void* gp, void* lp){
  __builtin_amdgcn_global_load_lds((const __attribute__((address_space(1))) u32*)gp,
                                   (__attribute__((address_space(3))) u32*)lp, 16, 0, 0);
}

// ---------- prep: s -> S16 (linear), S16s ([b][uc][u'][swz j]), Stp ([b][uc][j][perm u']) ----------
// perm-u order within 32 shorts: slot g (16B) = { 4g..4g+3, 16+4g..16+4g+3 }  (matches PA k-order)
__global__ __launch_bounds__(256) void k_prep_s(const float* __restrict__ s, short* __restrict__ S16,
                                                short* __restrict__ S16s, short* __restrict__ Stp){
  __shared__ float t[32][257];
  int b = blockIdx.x >> 5, tc = blockIdx.x & 31;
  const float* sp = s + ((size_t)b*1024 + tc*32)*256;
  int tid = threadIdx.x;
#pragma unroll
  for (int k = 0; k < 8; k++){
    int idx = tid + k*256;              // 2048 float4 = 32 rows x 64
    int row = idx >> 6, c4 = (idx & 63) * 4;
    float4 v = reinterpret_cast<const float4*>(sp)[idx];
    t[row][c4+0] = v.x; t[row][c4+1] = v.y; t[row][c4+2] = v.z; t[row][c4+3] = v.w;
  }
  __syncthreads();
  // A: linear + swizzled row copies
  {
    int r = tid >> 3, cg = tid & 7;
    short* lrow = S16 + ((size_t)b*1024 + tc*32 + r)*256 + cg*32;
    short* srow = S16s + (size_t)b*262144 + tc*8192 + r*256;
#pragma unroll
    for (int m = 0; m < 4; m++){
      bf16x8 o;
#pragma unroll
      for (int e = 0; e < 8; e++) o[e] = f2bf(t[r][cg*32 + m*8 + e]);
      *reinterpret_cast<bf16x8*>(lrow + m*8) = o;
      int slot = cg*4 + m;
      *reinterpret_cast<bf16x8*>(srow + ((slot ^ (r&7)) << 3)) = o;
    }
  }
  // B: perm-u transpose for PV global fragments
  {
    int j = tid;
    short* orow = Stp + (size_t)b*262144 + tc*8192 + j*32;
#pragma unroll
    for (int g = 0; g < 4; g++){
      bf16x8 o;
#pragma unroll
      for (int q = 0; q < 4; q++){
        o[q]   = f2bf(t[g*4+q][j]);
        o[4+q] = f2bf(t[16+g*4+q][j]);
      }
      *reinterpret_cast<bf16x8*>(orow + g*8) = o;
    }
  }
}

// ---------- prep: E -> bf16, pre-swizzled per 64-col block ----------
__global__ __launch_bounds__(256) void k_cvtE(const float* __restrict__ in, short* __restrict__ out){
  int i = blockIdx.x * 256 + threadIdx.x;   // 131072
  int e = i * 4;
  float4 v = reinterpret_cast<const float4*>(in)[i];
  s16x4 o;
  o[0]=f2bf(v.x); o[1]=f2bf(v.y); o[2]=f2bf(v.z); o[3]=f2bf(v.w);
  int hi = e >> 8, j = e & 255;
  int pos = (j>>6)*64 + ((((j>>3)&7) ^ (hi&7)) << 3) + (j&7);
  *reinterpret_cast<s16x4*>(out + hi*256 + pos) = o;
}

// ---------- prep: Qt[h][j][i] = Q[h][i][j], bf16 ----------
__global__ __launch_bounds__(256) void k_qt(const float* __restrict__ Q, short* __restrict__ Qt){
  __shared__ float t[32][33];
  int bid = blockIdx.x;
  int h = bid >> 6, tj = (bid >> 3) & 7, ti = bid & 7;
  const float* q = Q + h * 65536;
  short* o = Qt + h * 65536;
  int tx = threadIdx.x & 31, ty = threadIdx.x >> 5;
#pragma unroll
  for (int rr = 0; rr < 4; rr++)
    t[ty + rr*8][tx] = q[(ti*32 + ty + rr*8)*256 + tj*32 + tx];
  __syncthreads();
#pragma unroll
  for (int rr = 0; rr < 4; rr++)
    o[(tj*32 + ty + rr*8)*256 + ti*32 + tx] = f2bf(t[tx][ty + rr*8]);
}

// ---------- qs GEMM: qs[bh][t][swz j] = sum_k S[t][k] * Qt[j][k] ----------
__global__ __launch_bounds__(256) void k_gemm_qs(const short* __restrict__ S, const short* __restrict__ W, short* __restrict__ C){
  __shared__ short At[128*64];
  __shared__ short Bt[128*64];
  int bh = blockIdx.y, b = bh >> 3, h = bh & 7;
  const short* A = S + (size_t)b*262144;
  const short* Bm = W + h*65536;
  short* Co = C + (size_t)bh*262144;
  int mt = blockIdx.x >> 1, nt = blockIdx.x & 1;
  int Mb = mt*128, Nb = nt*128;
  int tid = threadIdx.x, lane = tid & 63, wv = tid >> 6;
  int wm = wv >> 1, wn = wv & 1;
  int g = lane >> 4, r16 = lane & 15;
  f32x4 acc[4][4] = {};
  for (int kk = 0; kk < 4; kk++){
    __syncthreads();
    for (int c = tid; c < 1024; c += 256){
      int row = c >> 3, slot = c & 7;
      int ss = slot ^ (row & 7);
      *reinterpret_cast<i32x4*>(At + row*64 + ss*8) =
        *reinterpret_cast<const i32x4*>(A + (Mb+row)*256 + kk*64 + slot*8);
      *reinterpret_cast<i32x4*>(Bt + row*64 + ss*8) =
        *reinterpret_cast<const i32x4*>(Bm + (Nb+row)*256 + kk*64 + slot*8);
    }
    __syncthreads();
#pragma unroll
    for (int ks = 0; ks < 2; ks++){
      int slot = ks*4 + g;
      bf16x8 af[4], bf_[4];
#pragma unroll
      for (int fm = 0; fm < 4; fm++){
        int row = wm*64 + fm*16 + r16;
        af[fm] = *reinterpret_cast<const bf16x8*>(At + row*64 + (slot ^ (row & 7))*8);
      }
#pragma unroll
      for (int fn = 0; fn < 4; fn++){
        int row = wn*64 + fn*16 + r16;
        bf_[fn] = *reinterpret_cast<const bf16x8*>(Bt + row*64 + (slot ^ (row & 7))*8);
      }
#pragma unroll
      for (int fm = 0; fm < 4; fm++)
#pragma unroll
        for (int fn = 0; fn < 4; fn++)
          acc[fm][fn] = __builtin_amdgcn_mfma_f32_16x16x32_bf16(af[fm], bf_[fn], acc[fm][fn], 0, 0, 0);
    }
  }
#pragma unroll
  for (int fm = 0; fm < 4; fm++)
#pragma unroll
    for (int fn = 0; fn < 4; fn++)
#pragma unroll
      for (int rg = 0; rg < 4; rg++){
        int m = Mb + wm*64 + fm*16 + g*4 + rg;
        int n = Nb + wn*64 + fn*16 + r16;
        Co[m*256 + (((n>>3) ^ (m&7)) << 3) + (n&7)] = f2bf(acc[fm][fn][rg]);
      }
}

// ---------- phase 2: G[bh][t][j] = sum_{u<=t} Omega[t][u] * S[u][j] ----------
// grid 512: b(8) x pair(8) x h(8); 4 waves = (t-half 32) x (j-half 128)
// QK: A=st (LDS, dbuf gll16), B=Qr (regs). PV: A=masked Omega (regs), B=Stp (global->regs).
__global__ __launch_bounds__(256, 2) void k_attn(const short* __restrict__ Ss, const short* __restrict__ Stp,
                                                 const short* __restrict__ qs, short* __restrict__ G){
  __shared__ short st[2][8192];   // [u'][swz j], 16KB each
  int bI = blockIdx.x >> 6, p = (blockIdx.x >> 3) & 7, h = blockIdx.x & 7;
  int tid = threadIdx.x, lane = tid & 63, w = tid >> 6;
  int g = lane >> 4, r16 = lane & 15;
  int tw = w >> 1, jw = w & 1;
  int bh = bI*8 + h;
  const short* Sb = Ss + (size_t)bI*262144;
  const short* Tp = Stp + (size_t)bI*262144;
  int so = w*2048 + lane*8;     // per-lane staging src offset (shorts)
  int dofs = w*2048;            // wave-uniform LDS dest base (shorts); HW adds lane*16B
  const short* pvb = Tp + (size_t)(jw*128 + r16)*32 + g*8;

#define QK_ITER(STC) do {                                                          \
    _Pragma("unroll")                                                              \
    for (int ks = 0; ks < 8; ks++){                                                \
      int sl = ks*4 + g;                                                           \
      bf16x8 a0 = *reinterpret_cast<const bf16x8*>((STC) + r16*256 + ((sl ^ (r16&7)) << 3));        \
      bf16x8 a1 = *reinterpret_cast<const bf16x8*>((STC) + (16+r16)*256 + ((sl ^ (r16&7)) << 3));   \
      om[0][0] = __builtin_amdgcn_mfma_f32_16x16x32_bf16(a0, Qr[0][ks], om[0][0], 0, 0, 0);         \
      om[0][1] = __builtin_amdgcn_mfma_f32_16x16x32_bf16(a1, Qr[0][ks], om[0][1], 0, 0, 0);         \
      om[1][0] = __builtin_amdgcn_mfma_f32_16x16x32_bf16(a0, Qr[1][ks], om[1][0], 0, 0, 0);         \
      om[1][1] = __builtin_amdgcn_mfma_f32_16x16x32_bf16(a1, Qr[1][ks], om[1][1], 0, 0, 0);         \
    }                                                                              \
  } while(0)

#define ITER(UT, CUR) do {                                                         \
    int ub = (UT)*32;                                                              \
    bool live = (ub <= tbase + 31);                                                \
    bf16x8 pv[8];                                                                  \
    if (live){                                                                     \
      const short* pp = pvb + (size_t)(UT)*8192;                                   \
      _Pragma("unroll")                                                            \
      for (int n = 0; n < 8; n++) pv[n] = *reinterpret_cast<const bf16x8*>(pp + n*512); \
    }                                                                              \
    if ((UT) + 1 < nut){                                                           \
      const short* s1 = Sb + (size_t)((UT)+1)*8192 + so;                           \
      _Pragma("unroll")                                                            \
      for (int k = 0; k < 4; k++) gll16(s1 + k*512, &st[(CUR)^1][dofs + k*512]);   \
    }                                                                              \
    if (live){                                                                     \
      f32x4 om[2][2] = {};                                                         \
      __builtin_amdgcn_s_setprio(1);                                               \
      QK_ITER(st[(CUR)]);                                                          \
      __builtin_amdgcn_s_setprio(0);                                               \
      bf16x8 PA[2];                                                                \
      if (ub + 31 <= tbase){                                                       \
        _Pragma("unroll")                                                          \
        for (int ts = 0; ts < 2; ts++)                                             \
          _Pragma("unroll")                                                        \
          for (int m = 0; m < 8; m++) PA[ts][m] = f2bf(om[ts][m>>2][m&3]);         \
      } else {                                                                     \
        _Pragma("unroll")                                                          \
        for (int ts = 0; ts < 2; ts++){                                            \
          int tl = tbase + ts*16 + r16;                                            \
          _Pragma("unroll")                                                        \
          for (int us = 0; us < 2; us++)                                           \
            _Pragma("unroll")                                                      \
            for (int rg = 0; rg < 4; rg++){                                        \
              int u = ub + us*16 + g*4 + rg;                                       \
              PA[ts][us*4+rg] = f2bf((u <= tl) ? om[ts][us][rg] : 0.0f);           \
            }                                                                      \
        }                                                                          \
      }                                                                            \
      __builtin_amdgcn_s_setprio(1);                                               \
      _Pragma("unroll")                                                            \
      for (int n = 0; n < 8; n++){                                                 \
        racc[0][n] = __builtin_amdgcn_mfma_f32_16x16x32_bf16(PA[0], pv[n], racc[0][n], 0, 0, 0); \
        racc[1][n] = __builtin_amdgcn_mfma_f32_16x16x32_bf16(PA[1], pv[n], racc[1][n], 0, 0, 0); \
      }                                                                            \
      __builtin_amdgcn_s_setprio(0);                                               \
    }                                                                              \
    __syncthreads();                                                               \
  } while(0)

  for (int pass = 0; pass < 2; pass++){
    int T = pass ? (15 - p) : p;            // pair (p,15-p): 36 iters/block uniform
    int tbase = T*64 + tw*32;
    const short* qp = qs + ((size_t)bh*1024 + tbase)*256;
    bf16x8 Qr[2][8];
#pragma unroll
    for (int ts = 0; ts < 2; ts++)
#pragma unroll
      for (int ks = 0; ks < 8; ks++)
        Qr[ts][ks] = *reinterpret_cast<const bf16x8*>(qp + (ts*16 + r16)*256 + (((ks*4+g) ^ (r16&7)) << 3));
    int nut = 2*T + 2;
#pragma unroll
    for (int k = 0; k < 4; k++)             // stage tile 0 -> buf 0
      gll16(Sb + so + k*512, &st[0][dofs + k*512]);
    __syncthreads();
    f32x4 racc[2][8] = {};
    for (int ut = 0; ut < nut; ut += 2){
      ITER(ut, 0);
      ITER(ut+1, 1);
    }
    // epilogue: G bf16, pre-swizzled per 64-col block for k_out's A staging
    short* Gp = G + (size_t)bh*262144;
#pragma unroll
    for (int ts = 0; ts < 2; ts++)
#pragma unroll
      for (int rg = 0; rg < 4; rg++){
        int t = tbase + ts*16 + g*4 + rg;
#pragma unroll
        for (int n = 0; n < 8; n++){
          int j = jw*128 + n*16 + r16;
          int pos = (j>>6)*64 + ((((j>>3)&7) ^ (t&7)) << 3) + (j&7);
          Gp[t*256 + pos] = f2bf(racc[ts][n][rg]);
        }
      }
  }
#undef ITER
#undef QK_ITER
}

// ---------- phase 3: out[b][t][i] = sum_{h,j} G[bh][t][j] * E[h][i][j]  (K=2048) ----------
__global__ __launch_bounds__(256) void k_out(const short* __restrict__ G, const short* __restrict__ E,
                                             float* __restrict__ out){
  __shared__ short At[2][4096];
  __shared__ short Bt[2][4096];
  int bid = blockIdx.x;
  int bI = bid >> 6, mt = (bid >> 2) & 15, nt = bid & 3;
  int Mb = mt*64, Nb = nt*64;
  int tid = threadIdx.x, lane = tid & 63, w = tid >> 6;
  int g = lane >> 4, r16 = lane & 15;
  int wm = w >> 1, wn = w & 1;
  const short* Gb = G + (size_t)bI*8*262144;
  int arow = w*16 + (lane >> 3);
  int acol = (lane & 7) * 8;
  f32x4 acc[2][2] = {};
  {
    const short* Ah = Gb + (size_t)Mb*256;
    const short* Bh = E + (size_t)Nb*256;
#pragma unroll
    for (int ia = 0; ia < 2; ia++){
      gll16(Ah + (arow + ia*8)*256 + acol, &At[0][(w*2+ia)*512]);
      gll16(Bh + (arow + ia*8)*256 + acol, &Bt[0][(w*2+ia)*512]);
    }
  }
  __syncthreads();
  int cur = 0;
  for (int kk = 0; kk < 32; kk++){
    if (kk + 1 < 32){
      int h = (kk+1) >> 2, jb = ((kk+1) & 3) * 64;
      const short* Ah = Gb + (size_t)h*262144 + (size_t)Mb*256 + jb;
      const short* Bh = E + (size_t)h*65536 + (size_t)Nb*256 + jb;
      int nb = cur ^ 1;
#pragma unroll
      for (int ia = 0; ia < 2; ia++){
        gll16(Ah + (arow + ia*8)*256 + acol, &At[nb][(w*2+ia)*512]);
        gll16(Bh + (arow + ia*8)*256 + acol, &Bt[nb][(w*2+ia)*512]);
      }
    }
    const short* Ac = At[cur];
    const short* Bc = Bt[cur];
    __builtin_amdgcn_s_setprio(1);
#pragma unroll
    for (int ks = 0; ks < 2; ks++){
      bf16x8 af[2], bf_[2];
#pragma unroll
      for (int ms = 0; ms < 2; ms++){
        int row = wm*32 + ms*16 + r16;
        af[ms] = *reinterpret_cast<const bf16x8*>(Ac + row*64 + (((ks*4+g) ^ (row&7)) << 3));
      }
#pragma unroll
      for (int ns = 0; ns < 2; ns++){
        int row = wn*32 + ns*16 + r16;
        bf_[ns] = *reinterpret_cast<const bf16x8*>(Bc + row*64 + (((ks*4+g) ^ (row&7)) << 3));
      }
#pragma unroll
      for (int ms = 0; ms < 2; ms++)
#pragma unroll
        for (int ns = 0; ns < 2; ns++)
          acc[ms][ns] = __builtin_amdgcn_mfma_f32_16x16x32_bf16(af[ms], bf_[ns], acc[ms][ns], 0, 0, 0);
    }
    __builtin_amdgcn_s_setprio(0);
    __syncthreads();
    cur ^= 1;
  }
  float* ob = out + (size_t)bI*262144;
#pragma unroll
  for (int ms = 0; ms < 2; ms++)
#pragma unroll
    for (int ns = 0; ns < 2; ns++)
#pragma unroll
      for (int rg = 0; rg < 4; rg++)
        ob[(Mb + wm*32 + ms*16 + g*4 + rg)*256 + Nb + wn*32 + ns*16 + r16] = acc[ms][ns][rg];
}

extern "C" void kernel_launch(void* const* d_in, const int* in_sizes, int n_in,
                              void* d_out, int out_size, void* d_ws, size_t ws_size,
                              hipStream_t stream){
  (void)in_sizes; (void)n_in; (void)out_size; (void)ws_size;
  const float* s = (const float*)d_in[0];
  const float* Q = (const float*)d_in[1];
  const float* E = (const float*)d_in[2];
  float* out = (float*)d_out;
  char* ws = (char*)d_ws;
  // ws: S16 4MB | S16s 4MB | Stp 4MB | E16s 1MB | Qt 1MB | qs 32MB | G 32MB = 78MB
  short* S16  = (short*)(ws);
  short* S16s = (short*)(ws + 4194304);
  short* Stp  = (short*)(ws + 8388608);
  short* E16s = (short*)(ws + 12582912);
  short* Qt   = (short*)(ws + 13631488);
  short* qsb  = (short*)(ws + 14680064);
  short* G    = (short*)(ws + 48234496);

  k_prep_s<<<256, 256, 0, stream>>>(s, S16, S16s, Stp);
  k_cvtE  <<<512, 256, 0, stream>>>(E, E16s);
  k_qt    <<<512, 256, 0, stream>>>(Q, Qt);
  k_gemm_qs<<<dim3(16, 64), 256, 0, stream>>>(S16, Qt, qsb);
  k_attn  <<<512, 256, 0, stream>>>(S16s, Stp, qsb, G);
  k_out   <<<512, 256, 0, stream>>>(G, E16s, out);
}

// Round 5
// 167.500 us; speedup vs baseline: 1.1696x; 1.1696x over previous
//
#include <hip/hip_runtime.h>
#include <hip/hip_bf16.h>

typedef __attribute__((ext_vector_type(8)))  short bf16x8;
typedef __attribute__((ext_vector_type(4)))  short s16x4;
typedef __attribute__((ext_vector_type(4)))  float f32x4;
typedef __attribute__((ext_vector_type(16))) float f32x16;
typedef __attribute__((ext_vector_type(4)))  int   i32x4;
typedef unsigned int u32;

__device__ inline short f2bf(float f){
  union { float f; unsigned u; } v; v.f = f;
  unsigned r = v.u + 0x7fffu + ((v.u >> 16) & 1u);   // RNE
  return (short)(r >> 16);
}
__device__ __forceinline__ short f2bf_fast(float f){
  union { __hip_bfloat16 h; short s; } u; u.h = __float2bfloat16(f); return u.s;
}

__device__ __forceinline__ void gll16(const void* gp, void* lp){
  __builtin_amdgcn_global_load_lds((const __attribute__((address_space(1))) u32*)gp,
                                   (__attribute__((address_space(3))) u32*)lp, 16, 0, 0);
}

// ---------- merged prep ----------
// bid [0,256):   s -> S16 (linear bf16), S16s ([b][uc][u'][swz16B j]), Stp ([b][uc][4][j][8u-perm])
// bid [256,768): E -> E16s (swz-64 blocks)
// bid [768,1280): Q -> Qt (transpose bf16)
__global__ __launch_bounds__(256) void k_prep(const float* __restrict__ s, const float* __restrict__ Q,
                                              const float* __restrict__ E, short* __restrict__ S16,
                                              short* __restrict__ S16s, short* __restrict__ Stp,
                                              short* __restrict__ E16s, short* __restrict__ Qt){
  __shared__ float t[32][257];
  int bid = blockIdx.x, tid = threadIdx.x;
  if (bid < 256){
    int b = bid >> 5, tc = bid & 31;
    const float* sp = s + ((size_t)b*1024 + tc*32)*256;
#pragma unroll
    for (int k = 0; k < 8; k++){
      int idx = tid + k*256;              // 2048 float4 = 32 rows x 64
      int row = idx >> 6, c4 = (idx & 63) * 4;
      float4 v = reinterpret_cast<const float4*>(sp)[idx];
      t[row][c4+0] = v.x; t[row][c4+1] = v.y; t[row][c4+2] = v.z; t[row][c4+3] = v.w;
    }
    __syncthreads();
    {
      int r = tid >> 3, cg = tid & 7;
      short* lrow = S16 + ((size_t)b*1024 + tc*32 + r)*256 + cg*32;
      short* srow = S16s + (size_t)bid*8192 + r*256;
#pragma unroll
      for (int m = 0; m < 4; m++){
        bf16x8 o;
#pragma unroll
        for (int e = 0; e < 8; e++) o[e] = f2bf(t[r][cg*32 + m*8 + e]);
        *reinterpret_cast<bf16x8*>(lrow + m*8) = o;
        int slot = cg*4 + m;
        *reinterpret_cast<bf16x8*>(srow + ((slot ^ (r&7)) << 3)) = o;
      }
    }
    {   // Stp: sub-array sq = q*2+hi holds u = q*16 + hi*4 + e + (e&4)
      int j = tid;
      short* orow = Stp + (size_t)bid*8192;
#pragma unroll
      for (int sq = 0; sq < 4; sq++){
        bf16x8 o;
#pragma unroll
        for (int e = 0; e < 8; e++){
          int u = (sq>>1)*16 + (sq&1)*4 + e + (e&4);
          o[e] = f2bf(t[u][j]);
        }
        *reinterpret_cast<bf16x8*>(orow + sq*2048 + j*8) = o;
      }
    }
  } else if (bid < 768){
    int i = (bid - 256)*256 + tid;   // 131072
    int e = i * 4;
    float4 v = reinterpret_cast<const float4*>(E)[i];
    s16x4 o;
    o[0]=f2bf(v.x); o[1]=f2bf(v.y); o[2]=f2bf(v.z); o[3]=f2bf(v.w);
    int hi = e >> 8, j = e & 255;
    int pos = (j>>6)*64 + ((((j>>3)&7) ^ (hi&7)) << 3) + (j&7);
    *reinterpret_cast<s16x4*>(E16s + hi*256 + pos) = o;
  } else {
    int b2 = bid - 768;
    int h = b2 >> 6, tj = (b2 >> 3) & 7, ti = b2 & 7;
    const float* q = Q + h * 65536;
    short* o = Qt + h * 65536;
    int tx = tid & 31, ty = tid >> 5;
#pragma unroll
    for (int rr = 0; rr < 4; rr++)
      t[ty + rr*8][tx] = q[(ti*32 + ty + rr*8)*256 + tj*32 + tx];
    __syncthreads();
#pragma unroll
    for (int rr = 0; rr < 4; rr++)
      o[(tj*32 + ty + rr*8)*256 + ti*32 + tx] = f2bf(t[tx][ty + rr*8]);
  }
}

// ---------- qs GEMM: qs[bh][t][j] = sum_k S[t][k] * Qt[j][k]  (LINEAR out) ----------
__global__ __launch_bounds__(256) void k_gemm_qs(const short* __restrict__ S, const short* __restrict__ W, short* __restrict__ C){
  __shared__ short At[128*64];
  __shared__ short Bt[128*64];
  int bh = blockIdx.y, b = bh >> 3, h = bh & 7;
  const short* A = S + (size_t)b*262144;
  const short* Bm = W + h*65536;
  short* Co = C + (size_t)bh*262144;
  int mt = blockIdx.x >> 1, nt = blockIdx.x & 1;
  int Mb = mt*128, Nb = nt*128;
  int tid = threadIdx.x, lane = tid & 63, wv = tid >> 6;
  int wm = wv >> 1, wn = wv & 1;
  int g = lane >> 4, r16 = lane & 15;
  f32x4 acc[4][4] = {};
  for (int kk = 0; kk < 4; kk++){
    __syncthreads();
    for (int c = tid; c < 1024; c += 256){
      int row = c >> 3, slot = c & 7;
      int ss = slot ^ (row & 7);
      *reinterpret_cast<i32x4*>(At + row*64 + ss*8) =
        *reinterpret_cast<const i32x4*>(A + (Mb+row)*256 + kk*64 + slot*8);
      *reinterpret_cast<i32x4*>(Bt + row*64 + ss*8) =
        *reinterpret_cast<const i32x4*>(Bm + (Nb+row)*256 + kk*64 + slot*8);
    }
    __syncthreads();
#pragma unroll
    for (int ks = 0; ks < 2; ks++){
      int slot = ks*4 + g;
      bf16x8 af[4], bf_[4];
#pragma unroll
      for (int fm = 0; fm < 4; fm++){
        int row = wm*64 + fm*16 + r16;
        af[fm] = *reinterpret_cast<const bf16x8*>(At + row*64 + (slot ^ (row & 7))*8);
      }
#pragma unroll
      for (int fn = 0; fn < 4; fn++){
        int row = wn*64 + fn*16 + r16;
        bf_[fn] = *reinterpret_cast<const bf16x8*>(Bt + row*64 + (slot ^ (row & 7))*8);
      }
#pragma unroll
      for (int fm = 0; fm < 4; fm++)
#pragma unroll
        for (int fn = 0; fn < 4; fn++)
          acc[fm][fn] = __builtin_amdgcn_mfma_f32_16x16x32_bf16(af[fm], bf_[fn], acc[fm][fn], 0, 0, 0);
    }
  }
#pragma unroll
  for (int fm = 0; fm < 4; fm++)
#pragma unroll
    for (int fn = 0; fn < 4; fn++)
#pragma unroll
      for (int rg = 0; rg < 4; rg++){
        int m = Mb + wm*64 + fm*16 + g*4 + rg;
        int n = Nb + wn*64 + fn*16 + r16;
        Co[m*256 + n] = f2bf(acc[fm][fn][rg]);
      }
}

// ---------- phase 2: G[bh][t][j] = sum_{u<=t} Omega[t][u] * S[u][j] ----------
// grid 256: b(8) x pair(4) x h(8); 4 waves, BT=128 (wave = 32t x 256j, NO dup), BU=32, 32x32x16 MFMA
__global__ __launch_bounds__(256, 1) void k_attn(const short* __restrict__ Ss, const short* __restrict__ Sp,
                                                 const short* __restrict__ qs, short* __restrict__ G){
  __shared__ short st[2][8192];   // [u' 32][swz16B j 256], 16KB each
  __shared__ short sp[2][8192];   // [4][j 256][8 u-perm], 16KB each
  int bI = blockIdx.x >> 5, p = (blockIdx.x >> 3) & 3, h = blockIdx.x & 7;
  int tid = threadIdx.x, lane = tid & 63, w = tid >> 6;
  int l31 = lane & 31, hi = lane >> 5;
  int bh = bI*8 + h;
  const short* Sb = Ss + (size_t)bI*262144;
  const short* Tb = Sp + (size_t)bI*262144;
  const short* qsb = qs + (size_t)bh*262144;
  int so = w*2048 + lane*8;       // per-lane staging src offset (shorts)
  int dofs = w*2048;              // wave-uniform LDS dest base; HW adds lane*16B
  int xorb = l31 & 7;

#define ITER(UT, CUR) do {                                                                   \
    if ((UT) + 1 < nut){                                                                     \
      const short* s1 = Sb + (size_t)((UT)+1)*8192 + so;                                     \
      const short* t1 = Tb + (size_t)((UT)+1)*8192 + so;                                     \
      _Pragma("unroll")                                                                      \
      for (int k = 0; k < 4; k++){                                                           \
        gll16(s1 + k*512, &st[(CUR)^1][dofs + k*512]);                                       \
        gll16(t1 + k*512, &sp[(CUR)^1][dofs + k*512]);                                       \
      }                                                                                      \
    }                                                                                        \
    if ((UT)*32 <= tb_w + 31){                                                               \
      const short* stc = st[(CUR)]; const short* spc = sp[(CUR)];                            \
      f32x16 om = {};                                                                        \
      __builtin_amdgcn_s_setprio(1);                                                         \
      _Pragma("unroll")                                                                      \
      for (int ks = 0; ks < 16; ks++){                                                       \
        bf16x8 a = *reinterpret_cast<const bf16x8*>(stc + l31*256 + (((ks*2+hi) ^ xorb) << 3)); \
        om = __builtin_amdgcn_mfma_f32_32x32x16_bf16(a, Qr[ks], om, 0, 0, 0);                \
      }                                                                                      \
      __builtin_amdgcn_s_setprio(0);                                                         \
      bf16x8 PA0, PA1;                                                                       \
      int ub = (UT)*32;                                                                      \
      if (ub + 31 <= tb_w){                                                                  \
        _Pragma("unroll")                                                                    \
        for (int e = 0; e < 8; e++){ PA0[e] = f2bf_fast(om[e]); PA1[e] = f2bf_fast(om[8+e]); } \
      } else {                                                                               \
        _Pragma("unroll")                                                                    \
        for (int e = 0; e < 8; e++){                                                         \
          int du = ub + hi*4 + e + (e&4);                                                    \
          PA0[e] = f2bf_fast((du      <= t_lane) ? om[e]   : 0.0f);                          \
          PA1[e] = f2bf_fast((du + 16 <= t_lane) ? om[8+e] : 0.0f);                          \
        }                                                                                    \
      }                                                                                      \
      __builtin_amdgcn_s_setprio(1);                                                         \
      _Pragma("unroll")                                                                      \
      for (int n = 0; n < 8; n++){                                                           \
        int jr8 = (n*32 + l31)*8 + hi*2048;                                                  \
        bf16x8 b0 = *reinterpret_cast<const bf16x8*>(spc + jr8);                             \
        bf16x8 b1 = *reinterpret_cast<const bf16x8*>(spc + 4096 + jr8);                      \
        racc[n] = __builtin_amdgcn_mfma_f32_32x32x16_bf16(PA0, b0, racc[n], 0, 0, 0);        \
        racc[n] = __builtin_amdgcn_mfma_f32_32x32x16_bf16(PA1, b1, racc[n], 0, 0, 0);        \
      }                                                                                      \
      __builtin_amdgcn_s_setprio(0);                                                         \
    }                                                                                        \
    __syncthreads();                                                                         \
  } while(0)

  for (int pass = 0; pass < 2; pass++){
    int T = pass ? (7 - p) : p;          // pair (p,7-p): 36 iters/block uniform
    int tb_w = T*128 + w*32;             // this wave's 32-row t strip
    int t_lane = tb_w + l31;
    const short* qp = qsb + (size_t)(tb_w + l31)*256 + hi*8;
    bf16x8 Qr[16];
#pragma unroll
    for (int ks = 0; ks < 16; ks++)
      Qr[ks] = *reinterpret_cast<const bf16x8*>(qp + ks*16);
    int nut = 4*T + 4;
#pragma unroll
    for (int k = 0; k < 4; k++){         // stage tile 0 -> buf 0
      gll16(Sb + so + k*512, &st[0][dofs + k*512]);
      gll16(Tb + so + k*512, &sp[0][dofs + k*512]);
    }
    __syncthreads();
    f32x16 racc[8] = {};
    for (int ut = 0; ut < nut; ut += 2){
      ITER(ut, 0);
      ITER(ut+1, 1);
    }
    // epilogue: G bf16 [t][swz-64 j] for k_out's A staging
    short* Gp = G + (size_t)bh*262144;
#pragma unroll
    for (int n = 0; n < 8; n++){
      int j = n*32 + l31;
#pragma unroll
      for (int r = 0; r < 16; r++){
        int t = tb_w + (r&3) + 8*(r>>2) + 4*hi;
        int pos = (j>>6)*64 + ((((j>>3)&7) ^ (t&7)) << 3) + (j&7);
        Gp[t*256 + pos] = f2bf_fast(racc[n][r]);
      }
    }
  }
#undef ITER
}

// ---------- phase 3: out[b][t][i] = sum_{h,j} G[bh][t][j] * E[h][i][j]  (K=2048) ----------
__global__ __launch_bounds__(256) void k_out(const short* __restrict__ G, const short* __restrict__ E,
                                             float* __restrict__ out){
  __shared__ short At[2][4096];
  __shared__ short Bt[2][4096];
  int bid = blockIdx.x;
  int bI = bid >> 6, mt = (bid >> 2) & 15, nt = bid & 3;
  int Mb = mt*64, Nb = nt*64;
  int tid = threadIdx.x, lane = tid & 63, w = tid >> 6;
  int g = lane >> 4, r16 = lane & 15;
  int wm = w >> 1, wn = w & 1;
  const short* Gb = G + (size_t)bI*8*262144;
  int arow = w*16 + (lane >> 3);
  int acol = (lane & 7) * 8;
  f32x4 acc[2][2] = {};
  {
    const short* Ah = Gb + (size_t)Mb*256;
    const short* Bh = E + (size_t)Nb*256;
#pragma unroll
    for (int ia = 0; ia < 2; ia++){
      gll16(Ah + (arow + ia*8)*256 + acol, &At[0][(w*2+ia)*512]);
      gll16(Bh + (arow + ia*8)*256 + acol, &Bt[0][(w*2+ia)*512]);
    }
  }
  __syncthreads();
  int cur = 0;
  for (int kk = 0; kk < 32; kk++){
    if (kk + 1 < 32){
      int h = (kk+1) >> 2, jb = ((kk+1) & 3) * 64;
      const short* Ah = Gb + (size_t)h*262144 + (size_t)Mb*256 + jb;
      const short* Bh = E + (size_t)h*65536 + (size_t)Nb*256 + jb;
      int nb = cur ^ 1;
#pragma unroll
      for (int ia = 0; ia < 2; ia++){
        gll16(Ah + (arow + ia*8)*256 + acol, &At[nb][(w*2+ia)*512]);
        gll16(Bh + (arow + ia*8)*256 + acol, &Bt[nb][(w*2+ia)*512]);
      }
    }
    const short* Ac = At[cur];
    const short* Bc = Bt[cur];
    __builtin_amdgcn_s_setprio(1);
#pragma unroll
    for (int ks = 0; ks < 2; ks++){
      bf16x8 af[2], bf_[2];
#pragma unroll
      for (int ms = 0; ms < 2; ms++){
        int row = wm*32 + ms*16 + r16;
        af[ms] = *reinterpret_cast<const bf16x8*>(Ac + row*64 + (((ks*4+g) ^ (row&7)) << 3));
      }
#pragma unroll
      for (int ns = 0; ns < 2; ns++){
        int row = wn*32 + ns*16 + r16;
        bf_[ns] = *reinterpret_cast<const bf16x8*>(Bc + row*64 + (((ks*4+g) ^ (row&7)) << 3));
      }
#pragma unroll
      for (int ms = 0; ms < 2; ms++)
#pragma unroll
        for (int ns = 0; ns < 2; ns++)
          acc[ms][ns] = __builtin_amdgcn_mfma_f32_16x16x32_bf16(af[ms], bf_[ns], acc[ms][ns], 0, 0, 0);
    }
    __builtin_amdgcn_s_setprio(0);
    __syncthreads();
    cur ^= 1;
  }
  float* ob = out + (size_t)bI*262144;
#pragma unroll
  for (int ms = 0; ms < 2; ms++)
#pragma unroll
    for (int ns = 0; ns < 2; ns++)
#pragma unroll
      for (int rg = 0; rg < 4; rg++)
        ob[(Mb + wm*32 + ms*16 + g*4 + rg)*256 + Nb + wn*32 + ns*16 + r16] = acc[ms][ns][rg];
}

extern "C" void kernel_launch(void* const* d_in, const int* in_sizes, int n_in,
                              void* d_out, int out_size, void* d_ws, size_t ws_size,
                              hipStream_t stream){
  (void)in_sizes; (void)n_in; (void)out_size; (void)ws_size;
  const float* s = (const float*)d_in[0];
  const float* Q = (const float*)d_in[1];
  const float* E = (const float*)d_in[2];
  float* out = (float*)d_out;
  char* ws = (char*)d_ws;
  // ws: S16 4MB | S16s 4MB | Stp 4MB | E16s 1MB | Qt 1MB | qs 32MB | G 32MB = 78MB
  short* S16  = (short*)(ws);
  short* S16s = (short*)(ws + 4194304);
  short* Stp  = (short*)(ws + 8388608);
  short* E16s = (short*)(ws + 12582912);
  short* Qt   = (short*)(ws + 13631488);
  short* qsb  = (short*)(ws + 14680064);
  short* G    = (short*)(ws + 48234496);

  k_prep<<<1280, 256, 0, stream>>>(s, Q, E, S16, S16s, Stp, E16s, Qt);
  k_gemm_qs<<<dim3(16, 64), 256, 0, stream>>>(S16, Qt, qsb);
  k_attn<<<256, 256, 0, stream>>>(S16s, Stp, qsb, G);
  k_out<<<512, 256, 0, stream>>>(G, E16s, out);
}